// Round 11
// baseline (497.971 us; speedup 1.0000x reference)
//
#include <hip/hip_runtime.h>
#include <math.h>

#define NF        128
#define HD        256
#define NA        200
#define BS        512
#define ALPHA_LR  0.01f
#define B_MIN_C   1e-4f

// LDS layout (dwords), total 20480 dw = 81920 B exactly -> 2 blocks/CU @160KB
#define PITCH     804                 // dwords per k-chunk (800 + 4 pad: odd bank phase for staging writes)
#define SLAB_DW   (24*PITCH + 800)    // 20096: chunks 0..23 padded, chunk 24 tail-trimmed
#define PH_DW     SLAB_DW             // solver: packed-f16 p vector, 100 dw (overlays MLP xs)
#define YV_DW     (SLAB_DW + 100)     // solver: fp32 y, 200 dw (overlays xs tail + hs)
#define XS_DW     SLAB_DW             // MLP: x, 128 dw
#define HS_DW     (SLAB_DW + 128)     // MLP: h, 256 dw
#define TOTAL_DW  20480
#define LDS_BYTES (TOTAL_DW * 4)      // 81920

#define N_PH1     10
#define N_REFINE  1
#define CG_MAX    40
#define TOL2_LO   4e-4f
#define TOL2_P1   1e-3f
#define TOL2_HI   2.5e-2f

typedef _Float16 h2_t __attribute__((ext_vector_type(2)));
typedef unsigned uv4  __attribute__((ext_vector_type(4)));

__device__ __forceinline__ h2_t as_h2(unsigned u){
  union { unsigned u; h2_t h; } c; c.u = u; return c.h;
}
__device__ __forceinline__ unsigned pk_f16(float a, float b){
#if __has_builtin(__builtin_amdgcn_cvt_pkrtz)
  union { decltype(__builtin_amdgcn_cvt_pkrtz(0.f, 0.f)) h; unsigned u; } c;
  c.h = __builtin_amdgcn_cvt_pkrtz(a, b);
  return c.u;
#else
  union { h2_t h; unsigned u; } c;
  c.h = (h2_t){ (_Float16)a, (_Float16)b };
  return c.u;
#endif
}
__device__ __forceinline__ float fdot2(unsigned m, unsigned v, float acc){
#if __has_builtin(__builtin_amdgcn_fdot2)
  return __builtin_amdgcn_fdot2(as_h2(m), as_h2(v), acc, false);
#else
  h2_t a = as_h2(m), b = as_h2(v);
  return fmaf((float)a.y, (float)b.y, fmaf((float)a.x, (float)b.x, acc));
#endif
}

// ---- DPP wave-64 reductions; result broadcast to all lanes via readlane ----
__device__ __forceinline__ float wave_allsum(float v){
  v += __int_as_float(__builtin_amdgcn_update_dpp(0, __float_as_int(v), 0x111, 0xf, 0xf, false));
  v += __int_as_float(__builtin_amdgcn_update_dpp(0, __float_as_int(v), 0x112, 0xf, 0xf, false));
  v += __int_as_float(__builtin_amdgcn_update_dpp(0, __float_as_int(v), 0x114, 0xf, 0xf, false));
  v += __int_as_float(__builtin_amdgcn_update_dpp(0, __float_as_int(v), 0x118, 0xf, 0xf, false));
  v += __int_as_float(__builtin_amdgcn_update_dpp(0, __float_as_int(v), 0x142, 0xa, 0xf, false));
  v += __int_as_float(__builtin_amdgcn_update_dpp(0, __float_as_int(v), 0x143, 0xc, 0xf, false));
  return __int_as_float(__builtin_amdgcn_readlane(__float_as_int(v), 63));
}
__device__ __forceinline__ float wave_allmin(float v){
  const int PINF = 0x7f800000;
  v = fminf(v, __int_as_float(__builtin_amdgcn_update_dpp(PINF, __float_as_int(v), 0x111, 0xf, 0xf, false)));
  v = fminf(v, __int_as_float(__builtin_amdgcn_update_dpp(PINF, __float_as_int(v), 0x112, 0xf, 0xf, false)));
  v = fminf(v, __int_as_float(__builtin_amdgcn_update_dpp(PINF, __float_as_int(v), 0x114, 0xf, 0xf, false)));
  v = fminf(v, __int_as_float(__builtin_amdgcn_update_dpp(PINF, __float_as_int(v), 0x118, 0xf, 0xf, false)));
  v = fminf(v, __int_as_float(__builtin_amdgcn_update_dpp(PINF, __float_as_int(v), 0x142, 0xa, 0xf, false)));
  v = fminf(v, __int_as_float(__builtin_amdgcn_update_dpp(PINF, __float_as_int(v), 0x143, 0xc, 0xf, false)));
  return __int_as_float(__builtin_amdgcn_readlane(__float_as_int(v), 63));
}
__device__ __forceinline__ float wave_allmax(float v){
  const int NINF = 0xff800000;
  v = fmaxf(v, __int_as_float(__builtin_amdgcn_update_dpp(NINF, __float_as_int(v), 0x111, 0xf, 0xf, false)));
  v = fmaxf(v, __int_as_float(__builtin_amdgcn_update_dpp(NINF, __float_as_int(v), 0x112, 0xf, 0xf, false)));
  v = fmaxf(v, __int_as_float(__builtin_amdgcn_update_dpp(NINF, __float_as_int(v), 0x114, 0xf, 0xf, false)));
  v = fmaxf(v, __int_as_float(__builtin_amdgcn_update_dpp(NINF, __float_as_int(v), 0x118, 0xf, 0xf, false)));
  v = fmaxf(v, __int_as_float(__builtin_amdgcn_update_dpp(NINF, __float_as_int(v), 0x142, 0xa, 0xf, false)));
  v = fmaxf(v, __int_as_float(__builtin_amdgcn_update_dpp(NINF, __float_as_int(v), 0x143, 0xc, 0xf, false)));
  return __int_as_float(__builtin_amdgcn_readlane(__float_as_int(v), 63));
}

// f16 matvec q = S_f16 * p (p packed f16 in ph). Lane-consecutive b128 slab
// reads (conflict-free); ph reads are wave-broadcast. Slot 3 read is
// unconditional (stays inside the 81920B allocation; garbage is masked).
__device__ __forceinline__ void mv_cg(const unsigned* __restrict__ slab,
                                      const unsigned* __restrict__ ph,
                                      int lane, float q[4]){
  const uv4* ph4 = (const uv4*)ph;
  float qa0=0.f,qb0=0.f,qa1=0.f,qb1=0.f,qa2=0.f,qb2=0.f,qa3=0.f,qb3=0.f;
  #pragma unroll 5
  for (int k = 0; k < 25; ++k){
    uv4 vv = ph4[k];
    const uv4* base = (const uv4*)(slab + k*PITCH);
    uv4 m0 = base[lane], m1 = base[lane+64], m2 = base[lane+128], m3 = base[lane+192];
    qa0=fdot2(m0.x,vv.x,qa0); qb0=fdot2(m0.y,vv.y,qb0); qa0=fdot2(m0.z,vv.z,qa0); qb0=fdot2(m0.w,vv.w,qb0);
    qa1=fdot2(m1.x,vv.x,qa1); qb1=fdot2(m1.y,vv.y,qb1); qa1=fdot2(m1.z,vv.z,qa1); qb1=fdot2(m1.w,vv.w,qb1);
    qa2=fdot2(m2.x,vv.x,qa2); qb2=fdot2(m2.y,vv.y,qb2); qa2=fdot2(m2.z,vv.z,qa2); qb2=fdot2(m2.w,vv.w,qb2);
    qa3=fdot2(m3.x,vv.x,qa3); qb3=fdot2(m3.y,vv.y,qb3); qa3=fdot2(m3.z,vv.z,qa3); qb3=fdot2(m3.w,vv.w,qb3);
  }
  q[0]=qa0+qb0; q[1]=qa1+qb1; q[2]=qa2+qb2; q[3]=qa3+qb3;
}

// f16 matrix x fp32 y (phase-1 gradient: keeps the Newton fixed point free of
// y-quantization noise; only the matrix is f16)
__device__ __forceinline__ void mv_grad(const unsigned* __restrict__ slab,
                                        const float* __restrict__ yv,
                                        int lane, float q[4]){
  const float4* y4 = (const float4*)yv;
  float q0=0.f,q1=0.f,q2=0.f,q3=0.f;
  #pragma unroll 5
  for (int k = 0; k < 25; ++k){
    float4 ya = y4[2*k], yb = y4[2*k+1];
    const uv4* base = (const uv4*)(slab + k*PITCH);
    uv4 m0 = base[lane], m1 = base[lane+64], m2 = base[lane+128], m3 = base[lane+192];
    #define ACC8(mm, acc) { \
      h2_t h0=as_h2(mm.x),h1=as_h2(mm.y),h2v=as_h2(mm.z),h3v=as_h2(mm.w); \
      acc=fmaf((float)h0.x,ya.x,acc); acc=fmaf((float)h0.y,ya.y,acc); \
      acc=fmaf((float)h1.x,ya.z,acc); acc=fmaf((float)h1.y,ya.w,acc); \
      acc=fmaf((float)h2v.x,yb.x,acc); acc=fmaf((float)h2v.y,yb.y,acc); \
      acc=fmaf((float)h3v.x,yb.z,acc); acc=fmaf((float)h3v.y,yb.w,acc); }
    ACC8(m0, q0) ACC8(m1, q1) ACC8(m2, q2) ACC8(m3, q3)
    #undef ACC8
  }
  q[0]=q0; q[1]=q1; q[2]=q2; q[3]=q3;
}

extern "C" __global__ __launch_bounds__(64)   // 1 wave/block; NOTE: no 2nd arg
// (R4/R6: any waves-per-EU hint clamps VGPRs to 64 and spills -> GB of scratch)
void rb_kernel(const float* __restrict__ x,  const float* __restrict__ Sigma,
               const float* __restrict__ W1, const float* __restrict__ b1,
               const float* __restrict__ W2, const float* __restrict__ b2,
               float* __restrict__ out) {
  extern __shared__ __align__(16) char smem_raw[];
  unsigned* smem = (unsigned*)smem_raw;
  unsigned* slab = smem;                      // f16 Sigma, k-major
  float* xs = (float*)(smem + XS_DW);         // MLP only
  float* hs = (float*)(smem + HS_DW);         // MLP only
  unsigned* ph = smem + PH_DW;                // solver only (overlays xs)
  float* yv = (float*)(smem + YV_DW);         // solver only (overlays xs/hs)
  unsigned short* phs = (unsigned short*)ph;

  const int lane = threadIdx.x;               // block = 1 wave of 64
  const int s    = blockIdx.x;
  const bool v3  = lane < 8;                  // slot 3 = row 192+lane
  const float* S = Sigma + (size_t)s * NA * NA;

  // ---- stage Sigma -> f16 k-major slab (coalesced global float4 reads) ----
  {
    const float4* Sg4 = (const float4*)S;     // 10000 float4
    for (int i = lane; i < 10000; i += 64){
      float4 w = Sg4[i];
      int row = i / 50;
      int c   = i - row * 50;
      unsigned* dst = slab + (c >> 1) * PITCH + row * 4 + (c & 1) * 2;
      dst[0] = pk_f16(w.x, w.y);
      dst[1] = pk_f16(w.z, w.w);
    }
  }
  float sd[4];
  sd[0] = S[(size_t)lane * NA + lane];
  sd[1] = S[(size_t)(64 + lane) * NA + 64 + lane];
  sd[2] = S[(size_t)(128 + lane) * NA + 128 + lane];
  sd[3] = v3 ? S[(size_t)(192 + lane) * NA + 192 + lane] : 1.f;

  // ---- MLP (wave-synchronous LDS: no barriers anywhere in this kernel) ----
  xs[lane]      = x[s * NF + lane];
  xs[lane + 64] = x[s * NF + 64 + lane];
  float hreg[4];
  #pragma unroll
  for (int jm = 0; jm < 4; ++jm){
    int j = lane + 64 * jm;
    const float4* w4 = (const float4*)(W1 + (size_t)j * NF);
    const float4* x4 = (const float4*)xs;
    float a0=0.f,a1=0.f,a2=0.f,a3=0.f;
    #pragma unroll 8
    for (int kk = 0; kk < 32; ++kk){
      float4 w = w4[kk]; float4 xv = x4[kk];
      a0 = fmaf(w.x, xv.x, a0); a1 = fmaf(w.y, xv.y, a1);
      a2 = fmaf(w.z, xv.z, a2); a3 = fmaf(w.w, xv.w, a3);
    }
    float acc = b1[j] + (a0 + a1) + (a2 + a3);
    hreg[jm] = (acc >= 0.f) ? acc : ALPHA_LR * acc;
  }
  #pragma unroll
  for (int jm = 0; jm < 4; ++jm) hs[lane + 64 * jm] = hreg[jm];
  __builtin_amdgcn_sched_barrier(0);

  float lg[4];
  {
    const float4* h4 = (const float4*)hs;
    const float4* r0 = (const float4*)(W2 + (size_t)lane * HD);
    const float4* r1 = (const float4*)(W2 + (size_t)(64 + lane) * HD);
    const float4* r2 = (const float4*)(W2 + (size_t)(128 + lane) * HD);
    const float4* r3 = (const float4*)(W2 + (size_t)((v3 ? 192 + lane : lane)) * HD);
    float a0=0.f,a1=0.f,a2=0.f,a3=0.f;
    #pragma unroll 4
    for (int kk = 0; kk < 64; ++kk){
      float4 hv = h4[kk];
      float4 w0 = r0[kk], w1 = r1[kk], w2 = r2[kk], w3 = r3[kk];
      a0 = fmaf(w0.x,hv.x, fmaf(w0.y,hv.y, fmaf(w0.z,hv.z, fmaf(w0.w,hv.w, a0))));
      a1 = fmaf(w1.x,hv.x, fmaf(w1.y,hv.y, fmaf(w1.z,hv.z, fmaf(w1.w,hv.w, a1))));
      a2 = fmaf(w2.x,hv.x, fmaf(w2.y,hv.y, fmaf(w2.z,hv.z, fmaf(w2.w,hv.w, a2))));
      a3 = fmaf(w3.x,hv.x, fmaf(w3.y,hv.y, fmaf(w3.z,hv.z, fmaf(w3.w,hv.w, a3))));
    }
    lg[0] = a0 + b2[lane];
    lg[1] = a1 + b2[64 + lane];
    lg[2] = a2 + b2[128 + lane];
    lg[3] = v3 ? (a3 + b2[192 + lane]) : 0.f;
  }

  // ---- softmax -> b (output 2); clamp + renorm -> b_ ----
  float mloc = fmaxf(fmaxf(lg[0], lg[1]), lg[2]);
  if (v3) mloc = fmaxf(mloc, lg[3]);
  float mx = wave_allmax(mloc);
  float e0 = expf(lg[0]-mx), e1 = expf(lg[1]-mx), e2 = expf(lg[2]-mx);
  float e3 = v3 ? expf(lg[3]-mx) : 0.f;
  float es = wave_allsum(e0 + e1 + e2 + e3);
  float bo0 = e0/es, bo1 = e1/es, bo2 = e2/es, bo3 = e3/es;
  float* outb = out + (size_t)BS * NA + (size_t)s * NA;
  outb[lane] = bo0; outb[64+lane] = bo1; outb[128+lane] = bo2;
  if (v3) outb[192+lane] = bo3;
  float bc0 = fmaxf(bo0, B_MIN_C), bc1 = fmaxf(bo1, B_MIN_C);
  float bc2 = fmaxf(bo2, B_MIN_C), bc3 = fmaxf(bo3, B_MIN_C);
  float bsum = wave_allsum(bc0 + bc1 + bc2 + (v3 ? bc3 : 0.f));
  float b_[4] = { bc0/bsum, bc1/bsum, bc2/bsum, bc3/bsum };

  // ---- y0 = b / sqrt(b^T S b) ----
  float y_[4];
  phs[lane]      = (unsigned short)(pk_f16(b_[0], 0.f) & 0xffffu);
  phs[64+lane]   = (unsigned short)(pk_f16(b_[1], 0.f) & 0xffffu);
  phs[128+lane]  = (unsigned short)(pk_f16(b_[2], 0.f) & 0xffffu);
  if (v3) phs[192+lane] = (unsigned short)(pk_f16(b_[3], 0.f) & 0xffffu);
  __builtin_amdgcn_sched_barrier(0);
  {
    float q[4]; mv_cg(slab, ph, lane, q);
    float quad = wave_allsum(b_[0]*q[0] + b_[1]*q[1] + b_[2]*q[2]
                             + (v3 ? b_[3]*q[3] : 0.f));
    float isq = rsqrtf(quad);
    #pragma unroll
    for (int m = 0; m < 4; ++m) y_[m] = b_[m] * isq;
    yv[lane] = y_[0]; yv[64+lane] = y_[1]; yv[128+lane] = y_[2];
    if (v3) yv[192+lane] = y_[3];
  }

  // ---- damped inexact Newton (phase-1 f16 gradient, then 1 exact refine) ----
  float gg0 = 1.f;
  bool  ph1done = false;
  int   nexact  = 0;
  for (int it = 0; it < N_PH1 + N_REFINE; ++it){
    if (nexact >= N_REFINE) break;
    const bool exact = ph1done;
    if (exact) ++nexact;

    float q[4];
    __builtin_amdgcn_sched_barrier(0);
    if (exact){
      // exact fp32 gradient via symmetry: q_r = sum_c S[c][r] * y_c (coalesced)
      q[0]=q[1]=q[2]=q[3]=0.f;
      #pragma unroll 2
      for (int c = 0; c < NA; ++c){
        float yc = yv[c];
        const float* Sc = S + (size_t)c * NA;
        q[0] = fmaf(Sc[lane],      yc, q[0]);
        q[1] = fmaf(Sc[64+lane],   yc, q[1]);
        q[2] = fmaf(Sc[128+lane],  yc, q[2]);
        if (v3) q[3] = fmaf(Sc[192+lane], yc, q[3]);
      }
    } else {
      mv_grad(slab, yv, lane, q);
    }

    float g[4], d[4], mi[4];
    float pgg = 0.f, prz = 0.f;
    #pragma unroll
    for (int m = 0; m < 4; ++m){
      g[m]  = q[m] - b_[m] / y_[m];
      d[m]  = b_[m] / (y_[m] * y_[m]);
      mi[m] = 1.f / (sd[m] + d[m]);
      float c = g[m] * g[m];
      if (m < 3 || v3){ pgg += c; prz += c * mi[m]; }
    }
    float gg = wave_allsum(pgg);
    float rz = wave_allsum(prz);
    if (it == 0) gg0 = fmaxf(gg, 1e-30f);
    float tol2 = exact ? TOL2_LO
                       : fminf(TOL2_HI, fmaxf(TOL2_P1, 4.f * (gg / gg0)));

    if (gg > 1e-24f){
      const float cinv = rsqrtf(gg);
      const float csc  = sqrtf(gg);
      float r[4], dy[4], pj[4];
      #pragma unroll
      for (int m = 0; m < 4; ++m){
        r[m]  = -g[m] * cinv;
        pj[m] = mi[m] * r[m];
        dy[m] = 0.f;
      }
      phs[lane]     = (unsigned short)(pk_f16(pj[0], 0.f) & 0xffffu);
      phs[64+lane]  = (unsigned short)(pk_f16(pj[1], 0.f) & 0xffffu);
      phs[128+lane] = (unsigned short)(pk_f16(pj[2], 0.f) & 0xffffu);
      if (v3) phs[192+lane] = (unsigned short)(pk_f16(pj[3], 0.f) & 0xffffu);
      rz = rz * cinv * cinv;

      const float rz0 = rz;
      for (int j = 0; j < CG_MAX; ++j){
        __builtin_amdgcn_sched_barrier(0);
        float qc[4]; mv_cg(slab, ph, lane, qc);
        float qf[4], cpq = 0.f, crq = 0.f, cqq = 0.f;
        #pragma unroll
        for (int m = 0; m < 4; ++m){
          qf[m] = qc[m] + d[m] * pj[m];
          float u = mi[m] * qf[m];
          if (m < 3 || v3){
            cpq += pj[m] * qf[m]; crq += r[m] * u; cqq += qf[m] * u;
          }
        }
        float pq = wave_allsum(cpq);
        float rq = wave_allsum(crq);
        float qq = wave_allsum(cqq);
        float alpha = rz / pq;
        float rznew = fmaxf(fmaf(alpha*alpha, qq, fmaf(-2.f*alpha, rq, rz)), 0.f);
        #pragma unroll
        for (int m = 0; m < 4; ++m){
          dy[m] = fmaf(alpha, pj[m], dy[m]);
          r[m]  = fmaf(-alpha, qf[m], r[m]);
        }
        bool brk = (rznew <= tol2 * rz0) || (j == CG_MAX - 1);
        if (!brk){
          float beta = rznew / rz;
          #pragma unroll
          for (int m = 0; m < 4; ++m) pj[m] = fmaf(beta, pj[m], mi[m] * r[m]);
          phs[lane]     = (unsigned short)(pk_f16(pj[0], 0.f) & 0xffffu);
          phs[64+lane]  = (unsigned short)(pk_f16(pj[1], 0.f) & 0xffffu);
          phs[128+lane] = (unsigned short)(pk_f16(pj[2], 0.f) & 0xffffu);
          if (v3) phs[192+lane] = (unsigned short)(pk_f16(pj[3], 0.f) & 0xffffu);
        }
        rz = rznew;
        if (brk) break;
      }

      // damped step keeping y > 0 (reference semantics)
      float ratio = 1e30f;
      #pragma unroll
      for (int m = 0; m < 4; ++m){
        dy[m] *= csc;
        if ((m < 3 || v3) && dy[m] < 0.f) ratio = fminf(ratio, -y_[m] / dy[m]);
      }
      float mr = wave_allmin(ratio);
      float t  = fminf(1.f, 0.9f * mr);
      #pragma unroll
      for (int m = 0; m < 4; ++m) y_[m] = fmaxf(fmaf(t, dy[m], y_[m]), 1e-12f);
      yv[lane] = y_[0]; yv[64+lane] = y_[1]; yv[128+lane] = y_[2];
      if (v3) yv[192+lane] = y_[3];
    }

    if (!exact && (gg <= 1e-8f * gg0 || it + 1 >= N_PH1)) ph1done = true;
  }

  // ---- z = y / sum(y) (output 1) ----
  float ys = wave_allsum(y_[0] + y_[1] + y_[2] + (v3 ? y_[3] : 0.f));
  float* outz = out + (size_t)s * NA;
  outz[lane] = y_[0]/ys; outz[64+lane] = y_[1]/ys; outz[128+lane] = y_[2]/ys;
  if (v3) outz[192+lane] = y_[3]/ys;
}

extern "C" void kernel_launch(void* const* d_in, const int* in_sizes, int n_in,
                              void* d_out, int out_size, void* d_ws, size_t ws_size,
                              hipStream_t stream) {
  const float* x     = (const float*)d_in[0];
  const float* Sigma = (const float*)d_in[1];
  const float* W1    = (const float*)d_in[2];
  const float* b1    = (const float*)d_in[3];
  const float* W2    = (const float*)d_in[4];
  const float* b2    = (const float*)d_in[5];
  float* out = (float*)d_out;
  static int attr_set = 0;
  if (!attr_set) {   // host-side config; safe under graph capture (R2 precedent)
    hipFuncSetAttribute((const void*)rb_kernel,
                        hipFuncAttributeMaxDynamicSharedMemorySize, LDS_BYTES);
    attr_set = 1;
  }
  hipLaunchKernelGGL(rb_kernel, dim3(BS), dim3(64), LDS_BYTES, stream,
                     x, Sigma, W1, b1, W2, b2, out);
}

// Round 12
// 362.724 us; speedup vs baseline: 1.3729x; 1.3729x over previous
//
#include <hip/hip_runtime.h>
#include <math.h>

#define NF        128
#define H_DIM     256
#define NA        200
#define B_SAMPLES 512
#define ALPHA_LR  0.01f
#define B_MIN_C   1e-4f

#define NTHREADS  512
#define ROWS_PER_WAVE 25            // exact-path: 8 waves x 25 rows

#define N_PH1     10
#define N_REFINE  1
#define CG_MAX    40
#define TOL2_LO   4e-4f             // refinement CG tolerance
#define TOL2_P1   1e-3f             // phase-1 CG tolerance floor
#define TOL2_HI   2.5e-2f

typedef _Float16 h2_t __attribute__((ext_vector_type(2)));
typedef unsigned uv4  __attribute__((ext_vector_type(4)));
typedef unsigned uv2  __attribute__((ext_vector_type(2)));

__device__ __forceinline__ h2_t as_h2(unsigned u){
  union { unsigned u; h2_t h; } c; c.u = u; return c.h;
}
__device__ __forceinline__ unsigned pk_f16(float a, float b){
#if __has_builtin(__builtin_amdgcn_cvt_pkrtz)
  union { decltype(__builtin_amdgcn_cvt_pkrtz(0.f, 0.f)) h; unsigned u; } c;
  c.h = __builtin_amdgcn_cvt_pkrtz(a, b);
  return c.u;
#else
  union { h2_t h; unsigned u; } c;
  c.h = (h2_t){ (_Float16)a, (_Float16)b };
  return c.u;
#endif
}
__device__ __forceinline__ float fdot2(unsigned m, unsigned v, float acc){
#if __has_builtin(__builtin_amdgcn_fdot2)
  return __builtin_amdgcn_fdot2(as_h2(m), as_h2(v), acc, false);
#else
  h2_t a = as_h2(m), b = as_h2(v);
  return fmaf((float)a.y, (float)b.y, fmaf((float)a.x, (float)b.x, acc));
#endif
}

// ---------------- DPP wave-64 reductions (result valid in lane 63) --------
__device__ __forceinline__ float dpp_wave_sum(float v){
  v += __int_as_float(__builtin_amdgcn_update_dpp(0, __float_as_int(v), 0x111, 0xf, 0xf, false));
  v += __int_as_float(__builtin_amdgcn_update_dpp(0, __float_as_int(v), 0x112, 0xf, 0xf, false));
  v += __int_as_float(__builtin_amdgcn_update_dpp(0, __float_as_int(v), 0x114, 0xf, 0xf, false));
  v += __int_as_float(__builtin_amdgcn_update_dpp(0, __float_as_int(v), 0x118, 0xf, 0xf, false));
  v += __int_as_float(__builtin_amdgcn_update_dpp(0, __float_as_int(v), 0x142, 0xa, 0xf, false));
  v += __int_as_float(__builtin_amdgcn_update_dpp(0, __float_as_int(v), 0x143, 0xc, 0xf, false));
  return v;
}
__device__ __forceinline__ float dpp_wave_min(float v){
  const int PINF = 0x7f800000;
  v = fminf(v, __int_as_float(__builtin_amdgcn_update_dpp(PINF, __float_as_int(v), 0x111, 0xf, 0xf, false)));
  v = fminf(v, __int_as_float(__builtin_amdgcn_update_dpp(PINF, __float_as_int(v), 0x112, 0xf, 0xf, false)));
  v = fminf(v, __int_as_float(__builtin_amdgcn_update_dpp(PINF, __float_as_int(v), 0x114, 0xf, 0xf, false)));
  v = fminf(v, __int_as_float(__builtin_amdgcn_update_dpp(PINF, __float_as_int(v), 0x118, 0xf, 0xf, false)));
  v = fminf(v, __int_as_float(__builtin_amdgcn_update_dpp(PINF, __float_as_int(v), 0x142, 0xa, 0xf, false)));
  v = fminf(v, __int_as_float(__builtin_amdgcn_update_dpp(PINF, __float_as_int(v), 0x143, 0xc, 0xf, false)));
  return v;
}
__device__ __forceinline__ float dpp_wave_max(float v){
  const int NINF = 0xff800000;
  v = fmaxf(v, __int_as_float(__builtin_amdgcn_update_dpp(NINF, __float_as_int(v), 0x111, 0xf, 0xf, false)));
  v = fmaxf(v, __int_as_float(__builtin_amdgcn_update_dpp(NINF, __float_as_int(v), 0x112, 0xf, 0xf, false)));
  v = fmaxf(v, __int_as_float(__builtin_amdgcn_update_dpp(NINF, __float_as_int(v), 0x114, 0xf, 0xf, false)));
  v = fmaxf(v, __int_as_float(__builtin_amdgcn_update_dpp(NINF, __float_as_int(v), 0x118, 0xf, 0xf, false)));
  v = fmaxf(v, __int_as_float(__builtin_amdgcn_update_dpp(NINF, __float_as_int(v), 0x142, 0xa, 0xf, false)));
  v = fmaxf(v, __int_as_float(__builtin_amdgcn_update_dpp(NINF, __float_as_int(v), 0x143, 0xc, 0xf, false)));
  return v;
}
// block reductions (prologue only)
__device__ __forceinline__ float block_sum8(float v, float* red8, int tid){
  __syncthreads();
  v = dpp_wave_sum(v);
  if ((tid & 63) == 63) red8[tid >> 6] = v;
  __syncthreads();
  float o = red8[0];
  #pragma unroll
  for (int w = 1; w < 8; ++w) o += red8[w];
  return o;
}
__device__ __forceinline__ float block_max8(float v, float* red8, int tid){
  __syncthreads();
  v = dpp_wave_max(v);
  if ((tid & 63) == 63) red8[tid >> 6] = v;
  __syncthreads();
  float o = red8[0];
  #pragma unroll
  for (int w = 1; w < 8; ++w) o = fmaxf(o, red8[w]);
  return o;
}

// owner writes its f16 vector entry; halves padded to 56 dwords (16B aligned)
__device__ __forceinline__ void put_ph(unsigned short* phs, int row, float v){
  unsigned short h = (unsigned short)(pk_f16(v, 0.f) & 0xffffu);
  phs[(row < 100) ? row : (row + 12)] = h;     // rows>=100 live at shorts 112+
}

// packed-f16 matvec: 48 dwords from VGPRs + 2 from LDS (one ds_read_b64)
__device__ __forceinline__ float mv_dot2(const unsigned* mreg,
                                         const uv2* __restrict__ sl2,
                                         const unsigned* __restrict__ ph,
                                         int half){
  const uv4* v4 = (const uv4*)(ph + half * 56);
  float a0=0.f, a1=0.f, a2=0.f, a3=0.f;
  #pragma unroll
  for (int k = 0; k < 12; ++k){
    uv4 vv = v4[k];
    a0 = fdot2(mreg[4*k+0], vv.x, a0);
    a1 = fdot2(mreg[4*k+1], vv.y, a1);
    a2 = fdot2(mreg[4*k+2], vv.z, a2);
    a3 = fdot2(mreg[4*k+3], vv.w, a3);
  }
  { uv4 vv = v4[12]; uv2 mm = *sl2;
    a0 = fdot2(mm.x, vv.x, a0); a1 = fdot2(mm.y, vv.y, a1); }
  return (a0 + a1) + (a2 + a3);
}

// f16-matrix x fp32-vector (phase-1 gradient: exact fixed point of f16 system)
__device__ __forceinline__ float mv_f32v(const unsigned* mreg,
                                         const uv2* __restrict__ sl2,
                                         const float* __restrict__ vv,
                                         int half){
  const float4* v4 = (const float4*)(vv + half * 100);
  float a0=0.f, a1=0.f;
  #pragma unroll
  for (int k = 0; k < 12; ++k){
    float4 va = v4[2*k], vb = v4[2*k+1];
    h2_t m0 = as_h2(mreg[4*k+0]), m1 = as_h2(mreg[4*k+1]);
    h2_t m2 = as_h2(mreg[4*k+2]), m3 = as_h2(mreg[4*k+3]);
    a0 = fmaf((float)m0.x, va.x, a0); a1 = fmaf((float)m0.y, va.y, a1);
    a0 = fmaf((float)m1.x, va.z, a0); a1 = fmaf((float)m1.y, va.w, a1);
    a0 = fmaf((float)m2.x, vb.x, a0); a1 = fmaf((float)m2.y, vb.y, a1);
    a0 = fmaf((float)m3.x, vb.z, a0); a1 = fmaf((float)m3.y, vb.w, a1);
  }
  { float4 va = v4[24]; uv2 mm = *sl2;
    h2_t m0 = as_h2(mm.x), m1 = as_h2(mm.y);
    a0 = fmaf((float)m0.x, va.x, a0); a1 = fmaf((float)m0.y, va.y, a1);
    a0 = fmaf((float)m1.x, va.z, a0); a1 = fmaf((float)m1.y, va.w, a1); }
  return a0 + a1;
}

extern "C" __global__ __launch_bounds__(NTHREADS)   // NOTE: no 2nd arg — any
// waves-per-EU hint clamps the allocator to 64 VGPRs and spills mreg
// (R4/R6 evidence: WRITE_SIZE 33.7MB / 3.05GB). Plain form allocates ~100+.
void rb_kernel(const float* __restrict__ x,  const float* __restrict__ Sigma,
               const float* __restrict__ W1, const float* __restrict__ b1,
               const float* __restrict__ W2, const float* __restrict__ b2,
               float* __restrict__ out) {
  __shared__ __align__(16) uv2 slab2[400];            // 3.2 KB: last 2 dwords/thread
  __shared__ __align__(16) unsigned ph[112];          // packed f16 vec, 56/half
  __shared__ __align__(16) float yv[NA];
  __shared__ __align__(16) float partial[NA];
  __shared__ __align__(16) float bcv[NA];
  __shared__ float xs[NF];
  __shared__ float hs[H_DIM];
  __shared__ __align__(16) float4 red4[8];            // fused CG reduction slots
  __shared__ float redD[8], red8[8];

  const int tid  = threadIdx.x;
  const int s    = blockIdx.x;
  const bool act = tid < 400;
  const int row  = tid >> 1;              // valid when act
  const int half = tid & 1;
  const bool owner = act && (half == 0);
  const float* S = Sigma + (size_t)s * NA * NA;
  unsigned short* phs = (unsigned short*)ph;

  if (tid < NF) xs[tid] = x[s * NF + tid];
  float sd = 0.f;
  if (owner) sd = S[(size_t)row * NA + row];

  // ---- stage Sigma (packed f16): 48 dwords -> VGPRs, 2 -> slab2 ----
  // Only the owning thread reads its slab2 entry -> no staging barriers.
  unsigned mreg[48];
  const uv2* sl2 = slab2 + tid;
  if (act){
    const float4* rowp = (const float4*)S + (size_t)row * 50 + half * 25;
    #pragma unroll
    for (int k = 0; k < 24; ++k){
      float4 w = rowp[k];
      mreg[2*k]   = pk_f16(w.x, w.y);
      mreg[2*k+1] = pk_f16(w.z, w.w);
    }
    { float4 w = rowp[24];
      uv2 u; u.x = pk_f16(w.x, w.y); u.y = pk_f16(w.z, w.w);
      slab2[tid] = u; }
  }

  // ---- MLP ----
  __syncthreads();                        // xs visible
  if (tid < H_DIM){
    const float* w = W1 + tid * NF;
    float acc = b1[tid];
    #pragma unroll 8
    for (int j = 0; j < NF; ++j) acc += w[j] * xs[j];
    hs[tid] = (acc >= 0.f) ? acc : ALPHA_LR * acc;
  }
  __syncthreads();
  float logit = -INFINITY;
  if (tid < NA){
    const float* w = W2 + tid * H_DIM;
    float acc = b2[tid];
    #pragma unroll 8
    for (int j = 0; j < H_DIM; ++j) acc += w[j] * hs[j];
    logit = acc;
  }

  // ---- softmax -> b (output 2); clamp+renorm -> bcv ----
  float mx = block_max8(logit, red8, tid);
  float e  = (tid < NA) ? expf(logit - mx) : 0.f;
  float es = block_sum8(e, red8, tid);
  float bsoft = e / es;
  if (tid < NA) out[(size_t)B_SAMPLES * NA + (size_t)s * NA + tid] = bsoft;
  float bcl = fmaxf(bsoft, B_MIN_C);
  float bs  = block_sum8((tid < NA) ? bcl : 0.f, red8, tid);
  if (tid < NA) bcv[tid] = bcl / bs;
  __syncthreads();                               // bcv visible

  float b_ = owner ? bcv[row] : 0.f;
  float y  = 0.f;
  if (owner) put_ph(phs, row, b_);

  // ---- y0 = bc / sqrt(bc^T S bc) ----
  __syncthreads();                               // ph visible
  {
    float acc = act ? mv_dot2(mreg, sl2, ph, half) : 0.f;
    float q   = acc + __shfl_xor(acc, 1, 64);
    float wq  = dpp_wave_sum(owner ? b_ * q : 0.f);
    if ((tid & 63) == 63) red4[tid >> 6] = make_float4(wq, 0.f, 0.f, 0.f);
    __syncthreads();
    float quad = 0.f;
    #pragma unroll
    for (int w = 0; w < 8; ++w) quad += red4[w].x;
    if (owner){ y = b_ / sqrtf(quad); yv[row] = y; }
  }

  // ---- damped inexact Newton ----
  float gg0 = 1.f;
  bool  ph1done = false;
  int   nexact  = 0;
  for (int it = 0; it < N_PH1 + N_REFINE; ++it){
    if (nexact >= N_REFINE) break;
    const bool exact = ph1done;
    if (exact) ++nexact;

    // --- gradient matvec q = (S y)_row (fp32 y, f16 or exact matrix) ---
    float q = 0.f;
    if (exact){
      __syncthreads();                           // yv visible, partial free
      int lane = tid & 63, wid = tid >> 6;
      int r0 = wid * ROWS_PER_WAVE;
      for (int rr = r0; rr < r0 + ROWS_PER_WAVE; ++rr){
        const float* rowp = S + (size_t)rr * NA;
        float a = rowp[lane]*yv[lane] + rowp[lane+64]*yv[lane+64]
                + rowp[lane+128]*yv[lane+128];
        if (lane < NA - 192) a += rowp[lane+192]*yv[lane+192];
        a = dpp_wave_sum(a);
        if (lane == 63) partial[rr] = a;
      }
      __syncthreads();
      if (owner) q = partial[row];
    } else {
      __syncthreads();                           // yv visible
      float acc = act ? mv_f32v(mreg, sl2, yv, half) : 0.f;
      q = acc + __shfl_xor(acc, 1, 64);
    }

    // --- Newton init; reduce gg and rz together ---
    float g=0.f, d=0.f, mi=0.f;
    if (owner){
      g  = q - b_ / y;
      d  = b_ / (y * y);
      mi = 1.f / (sd + d);
    }
    float wg = dpp_wave_sum(owner ? g * g : 0.f);
    float wz = dpp_wave_sum(owner ? g * g * mi : 0.f);   // rz = g^T M^-1 g
    if ((tid & 63) == 63) red4[tid >> 6] = make_float4(wg, wz, 0.f, 0.f);
    __syncthreads();
    float gg = 0.f, rz = 0.f;
    #pragma unroll
    for (int w = 0; w < 8; ++w){ float4 t = red4[w]; gg += t.x; rz += t.y; }
    if (it == 0) gg0 = fmaxf(gg, 1e-30f);
    float tol2 = exact ? TOL2_LO
                       : fminf(TOL2_HI, fmaxf(TOL2_P1, 4.f * (gg / gg0)));

    if (gg > 1e-24f){
      // --- scale CG system by 1/||g|| so packed-f16 p never underflows ---
      const float cinv = rsqrtf(gg);
      const float csc  = sqrtf(gg);
      float r=0.f, z=0.f, dy=0.f, pj=0.f;
      if (owner){
        r  = -g * cinv;
        z  = mi * r;
        pj = z;
        put_ph(phs, row, pj);
      }
      rz = rz * cinv * cinv;

      // --- Jacobi-PCG, fused single reduction (pq, rq, qq in one float4) ---
      const float rz0 = rz;
      for (int j = 0; j < CG_MAX; ++j){
        __syncthreads();                         // B1: ph visible, red4 reuse safe
        float acc = act ? mv_dot2(mreg, sl2, ph, half) : 0.f;
        float qp  = acc + __shfl_xor(acc, 1, 64);
        float qf=0.f, cpq=0.f, crq=0.f, cqq=0.f;
        if (owner){
          qf = qp + d * pj;
          float u = mi * qf;
          cpq = pj * qf; crq = r * u; cqq = qf * u;
        }
        cpq = dpp_wave_sum(cpq); crq = dpp_wave_sum(crq); cqq = dpp_wave_sum(cqq);
        if ((tid & 63) == 63) red4[tid >> 6] = make_float4(cpq, crq, cqq, 0.f);
        __syncthreads();                         // B2
        float pq = 0.f, rq = 0.f, qq = 0.f;
        #pragma unroll
        for (int w = 0; w < 8; ++w){ float4 t = red4[w]; pq += t.x; rq += t.y; qq += t.z; }
        float alpha = rz / pq;
        float rznew = fmaxf(fmaf(alpha*alpha, qq, fmaf(-2.f*alpha, rq, rz)), 0.f);
        if (owner){
          dy = fmaf(alpha, pj, dy);
          r  = fmaf(-alpha, qf, r);
          z  = mi * r;
        }
        bool brk = (rznew <= tol2 * rz0) || (j == CG_MAX - 1);
        if (!brk){
          float beta = rznew / rz;
          if (owner){ pj = fmaf(beta, pj, z); put_ph(phs, row, pj); }
        }
        rz = rznew;
        if (brk) break;
      }

      // --- unscale dy; damped step keeping y > 0 (reference semantics) ---
      if (owner) dy *= csc;
      float ratio = (owner && dy < 0.f) ? (-y / dy) : 1e30f;
      float wmn = dpp_wave_min(ratio);
      if ((tid & 63) == 63) redD[tid >> 6] = wmn;
      __syncthreads();
      float mr = fminf(fminf(fminf(redD[0],redD[1]),fminf(redD[2],redD[3])),
                       fminf(fminf(redD[4],redD[5]),fminf(redD[6],redD[7])));
      float t = fminf(1.f, 0.9f * mr);
      if (owner){
        y = fmaxf(fmaf(t, dy, y), 1e-12f);
        yv[row] = y;
        put_ph(phs, row, y);                     // repack y for next f16 use
      }
    }

    if (!exact && (gg <= 1e-8f * gg0 || it + 1 >= N_PH1)) ph1done = true;
  }

  // ---- z = y / sum(y) (output 1) ----
  float wy = dpp_wave_sum(owner ? y : 0.f);
  if ((tid & 63) == 63) red4[tid >> 6] = make_float4(wy, 0.f, 0.f, 0.f);
  __syncthreads();
  float ys = 0.f;
  #pragma unroll
  for (int w = 0; w < 8; ++w) ys += red4[w].x;
  if (owner) out[(size_t)s * NA + row] = y / ys;
}

extern "C" void kernel_launch(void* const* d_in, const int* in_sizes, int n_in,
                              void* d_out, int out_size, void* d_ws, size_t ws_size,
                              hipStream_t stream) {
  const float* x     = (const float*)d_in[0];
  const float* Sigma = (const float*)d_in[1];
  const float* W1    = (const float*)d_in[2];
  const float* b1    = (const float*)d_in[3];
  const float* W2    = (const float*)d_in[4];
  const float* b2    = (const float*)d_in[5];
  float* out = (float*)d_out;
  hipLaunchKernelGGL(rb_kernel, dim3(B_SAMPLES), dim3(NTHREADS), 0, stream,
                     x, Sigma, W1, b1, W2, b2, out);
}